// Round 9
// baseline (991.096 us; speedup 1.0000x reference)
//
#include <hip/hip_runtime.h>
#include <stdint.h>

#define B_   8
#define T_   2048
#define D_   1024
#define DFF_ 4096
#define M_   (B_ * T_)   // 16384

typedef __bf16 bf16;
typedef bf16  bf16x8 __attribute__((ext_vector_type(8)));
typedef bf16  bf16x4 __attribute__((ext_vector_type(4)));
typedef float f32x4  __attribute__((ext_vector_type(4)));

#define CAST_LDS(p) ((__attribute__((address_space(3))) void*)(p))
#define CAST_GLB(p) ((const __attribute__((address_space(1))) void*)(p))

// ---------------------------------------------------------------------------
// Fused prep kernel: cat16 weight cvt (3 tensors) + plain cvt (ffn_d) +
// RMSNorm1 — all independent, one launch.  (unchanged, verified)
// ---------------------------------------------------------------------------
struct PrepArgs {
    const float* w1[3];
    const float* w2[3];
    bf16* dst[3];
    int end[3];            // {2048, 4096, 12288}
    const float* fd;       // ffn_d_w fp32
    bf16* fdd;             // -> wd
    const float* x;
    const float* rw1;
    bf16* y1;
};

__global__ __launch_bounds__(256) void prep_kernel(PrepArgs a) {
    __shared__ float red[4];
    const int blk = blockIdx.x;
    const int t = threadIdx.x;

    if (blk >= 16384) {   // ---- RMSNorm 1 (fp32 in -> bf16) ----
        const size_t row = blk - 16384;
        const float4 v = ((const float4*)(a.x + row * D_))[t];
        float ss = v.x * v.x + v.y * v.y + v.z * v.z + v.w * v.w;
#pragma unroll
        for (int off = 32; off; off >>= 1) ss += __shfl_down(ss, off);
        if ((t & 63) == 0) red[t >> 6] = ss;
        __syncthreads();
        const float total = red[0] + red[1] + red[2] + red[3];
        const float rstd = rsqrtf(total * (1.0f / (float)D_) + 1e-6f);
        const float4 wv = ((const float4*)a.rw1)[t];
        bf16x4 o;
        o[0] = (bf16)(v.x * rstd * wv.x);
        o[1] = (bf16)(v.y * rstd * wv.y);
        o[2] = (bf16)(v.z * rstd * wv.z);
        o[3] = (bf16)(v.w * rstd * wv.w);
        ((bf16x4*)(a.y1 + row * D_))[t] = o;
        return;
    }
    if (blk >= 12288) {   // ---- plain cvt: ffn_d ----
        const int i = ((blk - 12288) * 256 + t) * 4;
        const float4 v = *(const float4*)(a.fd + i);
        bf16x4 o;
        o[0] = (bf16)v.x; o[1] = (bf16)v.y; o[2] = (bf16)v.z; o[3] = (bf16)v.w;
        *(bf16x4*)(a.fdd + i) = o;
        return;
    }
    // ---- cat16 cvt ----
    const int seg = (blk >= a.end[0] ? 1 : 0) + (blk >= a.end[1] ? 1 : 0);
    const int d = blk - (seg ? a.end[seg - 1] : 0);
    const int rr = d & 31;
    const float* src = ((rr < 16) ? a.w1[seg] : a.w2[seg]) +
                       (size_t)(((d >> 5) << 4) + (d & 15)) * D_;
    bf16* dst = a.dst[seg] + (size_t)d * D_;
    const float4 v = ((const float4*)src)[t];
    bf16x4 o;
    o[0] = (bf16)v.x; o[1] = (bf16)v.y; o[2] = (bf16)v.z; o[3] = (bf16)v.w;
    ((bf16x4*)dst)[t] = o;
}

// ---------------------------------------------------------------------------
// RMSNorm bf16-in (x1 path) -> bf16 out   (unchanged, verified)
// ---------------------------------------------------------------------------
__global__ __launch_bounds__(256) void rmsnorm_bf_kernel(const bf16* __restrict__ x,
                                                         const float* __restrict__ w,
                                                         bf16* __restrict__ y) {
    const size_t row = blockIdx.x;
    const int t = threadIdx.x;
    const bf16x4 xv = ((const bf16x4*)(x + row * D_))[t];
    float f0 = (float)xv[0], f1 = (float)xv[1], f2 = (float)xv[2], f3 = (float)xv[3];
    float ss = f0 * f0 + f1 * f1 + f2 * f2 + f3 * f3;
#pragma unroll
    for (int off = 32; off; off >>= 1) ss += __shfl_down(ss, off);
    __shared__ float red[4];
    if ((t & 63) == 0) red[t >> 6] = ss;
    __syncthreads();
    const float total = red[0] + red[1] + red[2] + red[3];
    const float rstd = rsqrtf(total * (1.0f / (float)D_) + 1e-6f);
    const float4 wv = ((const float4*)w)[t];
    bf16x4 o;
    o[0] = (bf16)(f0 * rstd * wv.x);
    o[1] = (bf16)(f1 * rstd * wv.y);
    o[2] = (bf16)(f2 * rstd * wv.z);
    o[3] = (bf16)(f3 * rstd * wv.w);
    ((bf16x4*)(y + row * D_))[t] = o;
}

// ---------------------------------------------------------------------------
// Chunked fused liquid-tanh + PLIF scan.   (unchanged, verified)
// ---------------------------------------------------------------------------
#define SCAN_C  32
#define SCAN_L  (T_ / SCAN_C)   // 64
#define SCAN_W  32
#define SCAN_PF 8

template <int N, int W0>
__device__ __forceinline__ void scan_body(const uint32_t* __restrict__ p,
                                          bf16* __restrict__ o, const int ts,
                                          const float pdec, const float om,
                                          const float th) {
    uint32_t buf[SCAN_PF];
#pragma unroll
    for (int i = 0; i < SCAN_PF; ++i) buf[i] = p[(size_t)i * D_];
    float h = 0.0f, v = 0.0f;
#pragma unroll 8
    for (int k = 0; k < N; ++k) {
        const uint32_t w = buf[k & (SCAN_PF - 1)];
        if (k + SCAN_PF < N) buf[k & (SCAN_PF - 1)] = p[(size_t)(k + SCAN_PF) * D_];
        const float a  = __builtin_bit_cast(float, w << 16);
        const float bb = __builtin_bit_cast(float, w & 0xffff0000u);
        const float xv = fmaf(a, h, bb);
        const float e2 = __expf(2.0f * xv);
        h = 1.0f - __fdividef(2.0f, 1.0f + e2);          // tanh(xv)
        const float vpre = fmaf(pdec, v, om * h);
        const float s = (vpre > th) ? 1.0f : 0.0f;
        v = vpre - s * th;
        if (k >= W0) o[(size_t)(ts + k) * D_] = (bf16)(s + h);
    }
}

__global__ __launch_bounds__(256) void scan_kernel(const uint32_t* __restrict__ ABp,
                                                   const float* __restrict__ log_tau,
                                                   const float* __restrict__ thr,
                                                   bf16* __restrict__ sp) {
    const int g = blockIdx.x * 256 + threadIdx.x;
    const int d = g & (D_ - 1);
    const int bc = g >> 10;
    const int b = bc / SCAN_C;
    const int c = bc % SCAN_C;
    const float pdec = __expf(-__expf(-log_tau[d]));
    const float om = 1.0f - pdec;
    const float th = thr[d];
    const int t0 = c * SCAN_L;
    const uint32_t* base = ABp + (size_t)b * (T_ * D_) + d;
    bf16* o = sp + (size_t)b * (T_ * D_) + d;
    if (c == 0) {
        scan_body<SCAN_L, 0>(base, o, 0, pdec, om, th);
    } else {
        const int ts = t0 - SCAN_W;
        scan_body<SCAN_L + SCAN_W, SCAN_W>(base + (size_t)ts * D_, o, ts, pdec, om, th);
    }
}

// ---------------------------------------------------------------------------
// PERSISTENT 128x128 GEMM, 2 BLOCKS/CU — round 9.
// Same verified ping-pong pipeline as round 5, reduced to 2 phases/K-step
// at a 128x128 tile (4 waves, 64KB LDS) so TWO independent blocks co-reside
// per CU.  Theory: round-8 accounting shows DS-read pipe (~564cy) and MFMA
// pipe (~592cy) serialize per phase in the 1-block lockstep (both utils 43%,
// sum==measured 1326cy); a second independent barrier group lets one block's
// MFMA cover the other's DS/stage/sync regions (m114/m97 mechanism).
// Slot liveness (4 slots [128][32] per operand, step parity*2 + khalf):
//  - cb+0 last read = PREF at ph2 of step s-1 -> free for ph1 STG(s+2,k0)
//  - cb+1 last read = PREF at ph1 of step s   -> free for ph2 STG(s+2,k1)
//  - vmcnt(8) at ph2 = exactly this step's 8 in-flight stages -> all older
//    stages (incl. step s+1's slots) landed before they are PREF'd.
// Registers: acc 64 AGPR + frags 64 VGPR + addr ~40 => ~170/256, headroom
// (eliminates the round-6/7 spill mode).
// MODE 0: delta/b -> pack bf16(A_t)|bf16(b_t)<<16 (u32)
// MODE 1: syn/gate -> out = x + syn*sigmoid(gate) (bf16)
// MODE 2: ffn g/u -> out = silu(g)*u (bf16)
// MODE 3: ffn down (no cat) -> out = x1 + acc (fp32)
// ---------------------------------------------------------------------------

#define STG_A(kt, slot)                                                                \
  { bf16* l_ = lA0 + (slot) * 4096;                                                    \
    const bf16* g_ = gA + (kt) * 64 + (((slot) & 1) << 5);                             \
    __builtin_amdgcn_global_load_lds(CAST_GLB(g_), CAST_LDS(l_), 16, 0, 0);            \
    __builtin_amdgcn_global_load_lds(CAST_GLB(g_ + g2), CAST_LDS(l_ + 2048), 16, 0, 0); }
#define STG_B(gb, kt, slot)                                                            \
  { bf16* l_ = lB0 + (slot) * 4096;                                                    \
    const bf16* g_ = (gb) + (kt) * 64 + (((slot) & 1) << 5);                           \
    __builtin_amdgcn_global_load_lds(CAST_GLB(g_), CAST_LDS(l_), 16, 0, 0);            \
    __builtin_amdgcn_global_load_lds(CAST_GLB(g_ + g2), CAST_LDS(l_ + 2048), 16, 0, 0); }
#define PREF_A(dst, slot)                                                              \
  { const bf16* As_ = smA + (slot) * 4096 + swz;                                       \
    _Pragma("unroll")                                                                  \
    for (int i = 0; i < 4; ++i)                                                        \
      dst[i] = *(const bf16x8*)(As_ + (wm + i * 16 + lane15) * 32);                    \
  }
#define PREF_B(dst, slot)                                                              \
  { const bf16* Bs_ = smB + (slot) * 4096 + swz;                                       \
    _Pragma("unroll")                                                                  \
    for (int j = 0; j < 4; ++j)                                                        \
      dst[j] = *(const bf16x8*)(Bs_ + (wn + j * 16 + lane15) * 32);                    \
  }
#define MFMA16(A_, B_)                                                                 \
  _Pragma("unroll")                                                                    \
  for (int i = 0; i < 4; ++i)                                                          \
    _Pragma("unroll")                                                                  \
    for (int j = 0; j < 4; ++j)                                                        \
      acc[i][j] = __builtin_amdgcn_mfma_f32_16x16x32_bf16(                             \
          A_[i], B_[j], acc[i][j], 0, 0, 0);
#define GBAR() __builtin_amdgcn_s_barrier()
#define LGKM0() asm volatile("s_waitcnt lgkmcnt(0)" ::: "memory")

template <int MODE>
__global__ __launch_bounds__(256, 2) void gemm128p_kernel(
    const bf16* __restrict__ A, const bf16* __restrict__ Bw,
    const int K, const int Nlog, const int NTN,   // NTN = N_cat / 128
    const float* __restrict__ b1, const float* __restrict__ b2,
    const float* __restrict__ extra, const bf16* __restrict__ extra_bf,
    void* __restrict__ outp) {
    __shared__ bf16 smem[32768] __attribute__((aligned(16)));   // 64 KiB
    bf16* const smA = smem;             // 4 slots x 4096 elems ([128][32] each)
    bf16* const smB = smem + 16384;

    const int tid = threadIdx.x;
    const int wave = tid >> 6;          // 0..3
    const int lane = tid & 63;
    const int lane15 = lane & 15;
    const int quad = lane >> 4;
    const int mr = wave >> 1;           // 0..1
    const int nc = wave & 1;            // 0..1
    const int wm = mr * 64;
    const int wn = nc * 64;
    const int swz = (quad ^ ((lane15 >> 1) & 3)) << 3;   // constant per lane

    // XCD map: 64 blocks/XCD (2/CU), 16-mt slab per XCD, 16mt x 4nt set.
    const int xcd = blockIdx.x & 7;
    const int cu  = blockIdx.x >> 3;     // 0..63
    const int mt  = xcd * 16 + (cu & 15);// fixed per block (M/128 = 128 tiles)
    const int nt0 = cu >> 4;             // 0..3
    const int TPB = NTN >> 2;
    const int NT  = K >> 6;
    const int S   = TPB * NT;

    const int srow = tid >> 2;                               // 0..63 (q=0)
    const int scol = (((tid & 3) ^ ((srow >> 1) & 3)) << 3); // pre-swizzled col
    const bf16* const gA = A + (size_t)(mt * 128 + srow) * K + scol;
    const size_t g2 = (size_t)64 * K;                        // q=1: rows +64
    const size_t dB = (size_t)512 * K;                       // nt += 4 per tile
    const bf16* gBc = Bw + (size_t)(nt0 * 128 + srow) * K + scol;
    bf16* const lA0 = smA + (wave << 9);   // wave*1024B = 512 elems
    bf16* const lB0 = smB + (wave << 9);

    f32x4 acc[4][4] = {};
    bf16x8 a0[4], a1[4], b0[4], b1_[4];

    // prologue: step 0 (slots 0,1) + step 1 (slots 2,3); oldest 8 drained.
    STG_B(gBc, 0, 0); STG_A(0, 0); STG_B(gBc, 0, 1); STG_A(0, 1);
    STG_B(gBc, 1, 2); STG_A(1, 2); STG_B(gBc, 1, 3); STG_A(1, 3);
    asm volatile("s_waitcnt vmcnt(8)" ::: "memory");
    GBAR();
    PREF_A(a0, 0); PREF_B(b0, 0);
    LGKM0();          // own reads done BEFORE barrier: no race with ph1 STG
    GBAR();

    for (int w = 0; w < TPB; ++w) {
        const bf16* const gBn = gBc + dB;   // next tile's B base
        for (int t = 0; t < NT; ++t) {
            const int s = w * NT + t;
            const int cb = (t & 1) << 1;    // this step's slots (s+2 shares them)
            const int nb = cb ^ 2;          // next step's slots
            const int tp2 = (t + 2 >= NT) ? t + 2 - NT : t + 2;
            const bf16* const gB2 = (t + 2 >= NT) ? gBn : gBc;
            const bool st2 = (s + 2 < S);

            // phase 1: stage (s+2,k0)->cb+0; compute k0; pref k1 frags
            if (st2) { STG_A(tp2, cb + 0); STG_B(gB2, tp2, cb + 0); }
            GBAR(); LGKM0();
            __builtin_amdgcn_s_setprio(1);
            PREF_A(a1, cb + 1); PREF_B(b1_, cb + 1);
            MFMA16(a0, b0);
            __builtin_amdgcn_s_setprio(0);
            GBAR();

            // phase 2: stage (s+2,k1)->cb+1; counted vmcnt; compute k1;
            //          pref next step's k0 frags
            if (st2) {
                STG_A(tp2, cb + 1); STG_B(gB2, tp2, cb + 1);
                asm volatile("s_waitcnt vmcnt(8)" ::: "memory");
            } else {
                asm volatile("s_waitcnt vmcnt(0)" ::: "memory");
            }
            GBAR(); LGKM0();
            __builtin_amdgcn_s_setprio(1);
            PREF_A(a0, nb + 0); PREF_B(b0, nb + 0);
            MFMA16(a1, b1_);
            __builtin_amdgcn_s_setprio(0);
            GBAR();
        }

        // ---- per-tile epilogue (register-local; LDS untouched) ----
        const int nt = nt0 + w * 4;
        if constexpr (MODE != 3) {
            // cat16: j even = W1, j odd = W2; logical col group
            // g = nt*4 + nc*2 + (j>>1)  ->  n = nt*64 + nc*32 + (j>>1)*16 + l15
            const int nlog0 = nt * 64 + nc * 32;
            const int mbase = mt * 128 + wm;
#pragma unroll
            for (int i = 0; i < 4; ++i)
#pragma unroll
                for (int jp = 0; jp < 2; ++jp)
#pragma unroll
                    for (int r = 0; r < 4; ++r) {
                        const int m = mbase + i * 16 + quad * 4 + r;
                        const int n = nlog0 + jp * 16 + lane15;
                        const size_t idx = (size_t)m * Nlog + n;
                        const float v1 = acc[i][jp * 2][r];      // W1 side
                        const float v2 = acc[i][jp * 2 + 1][r];  // W2 side
                        if constexpr (MODE == 0) {
                            const float dl = v1 + b1[n];
                            const float spv = (dl > 20.0f) ? dl : log1pf(__expf(dl));
                            const float bv = spv * (v2 + b2[n]);
                            const float av = __expf(-spv * __expf(extra[n]));
                            const uint32_t pa =
                                (uint32_t)__builtin_bit_cast(unsigned short, (bf16)av);
                            const uint32_t pb =
                                (uint32_t)__builtin_bit_cast(unsigned short, (bf16)bv);
                            ((uint32_t*)outp)[idx] = pa | (pb << 16);
                        } else if constexpr (MODE == 1) {
                            const float syn = v1 + b1[n];
                            const float z = v2 + b2[n];
                            const float gate = 1.0f / (1.0f + __expf(-z));
                            ((bf16*)outp)[idx] = (bf16)(extra[idx] + syn * gate);
                        } else {   // MODE 2
                            const float sg = v1 / (1.0f + __expf(-v1));
                            ((bf16*)outp)[idx] = (bf16)(sg * v2);
                        }
                    }
        } else {   // MODE 3: single-B, direct fp32 write
            const int mbase = mt * 128 + wm;
            const int nbase = nt * 128 + wn;
#pragma unroll
            for (int i = 0; i < 4; ++i)
#pragma unroll
                for (int j = 0; j < 4; ++j)
#pragma unroll
                    for (int r = 0; r < 4; ++r) {
                        const int m = mbase + i * 16 + quad * 4 + r;
                        const int n = nbase + j * 16 + lane15;
                        const size_t idx = (size_t)m * Nlog + n;
                        ((float*)outp)[idx] = (float)extra_bf[idx] + acc[i][j][r];
                    }
        }

        if (w + 1 < TPB) {
#pragma unroll
            for (int i = 0; i < 4; ++i)
#pragma unroll
                for (int j = 0; j < 4; ++j)
                    acc[i][j] = (f32x4){0.0f, 0.0f, 0.0f, 0.0f};
            gBc = gBn;
        }
    }
}

#undef STG_A
#undef STG_B
#undef PREF_A
#undef PREF_B
#undef MFMA16
#undef GBAR
#undef LGKM0

// ---------------------------------------------------------------------------
extern "C" void kernel_launch(void* const* d_in, const int* in_sizes, int n_in,
                              void* d_out, int out_size, void* d_ws, size_t ws_size,
                              hipStream_t stream) {
    const float* x        = (const float*)d_in[0];
    const float* rms_w1   = (const float*)d_in[1];
    const float* rms_w2   = (const float*)d_in[2];
    const float* delta_w  = (const float*)d_in[3];
    const float* delta_b  = (const float*)d_in[4];
    const float* b_w      = (const float*)d_in[5];
    const float* b_b      = (const float*)d_in[6];
    const float* A_log    = (const float*)d_in[7];
    const float* log_tau  = (const float*)d_in[8];
    const float* plif_thr = (const float*)d_in[9];
    const float* syn_w    = (const float*)d_in[10];
    const float* syn_b    = (const float*)d_in[11];
    const float* gate_w   = (const float*)d_in[12];
    const float* gate_b   = (const float*)d_in[13];
    const float* ffn_g_w  = (const float*)d_in[14];
    const float* ffn_u_w  = (const float*)d_in[15];
    const float* ffn_d_w  = (const float*)d_in[16];

    char* ws = (char*)d_ws;
    const size_t MB = 1024ull * 1024ull;
    // cat16-interleaved bf16 weights: [0,32MB)
    bf16* wcat_db = (bf16*)(ws + 0 * MB);    // [2048,1024]  4MB
    bf16* wcat_sg = (bf16*)(ws + 4 * MB);    // [2048,1024]  4MB
    bf16* wcat_gu = (bf16*)(ws + 8 * MB);    // [8192,1024] 16MB
    bf16* wd      = (bf16*)(ws + 24 * MB);   // [1024,4096]  8MB
    // phase-1 buffers (all dead before act is written):
    bf16*     y1      = (bf16*)(ws + 32 * MB);       // 32MB
    uint32_t* ABp     = (uint32_t*)(ws + 64 * MB);   // 64MB
    bf16*     spikein = (bf16*)(ws + 128 * MB);      // 32MB
    // persistent:
    bf16* x1 = (bf16*)(ws + 160 * MB);               // 32MB (bf16)
    bf16* y2 = (bf16*)(ws + 224 * MB);               // 32MB
    // act aliases the dead phase-1 region [32MB,160MB): 16384*4096*2 = 128MB
    bf16* act = (bf16*)(ws + 32 * MB);
    float* outF = (float*)d_out;

    // --- fused prep: weight converts + RMSNorm 1 (one launch) ---
    PrepArgs pa;
    pa.w1[0] = delta_w; pa.w2[0] = b_w;     pa.dst[0] = wcat_db;
    pa.w1[1] = syn_w;   pa.w2[1] = gate_w;  pa.dst[1] = wcat_sg;
    pa.w1[2] = ffn_g_w; pa.w2[2] = ffn_u_w; pa.dst[2] = wcat_gu;
    pa.end[0] = 2048; pa.end[1] = 4096; pa.end[2] = 12288;
    pa.fd = ffn_d_w; pa.fdd = wd;
    pa.x = x; pa.rw1 = rms_w1; pa.y1 = y1;
    prep_kernel<<<32768, 256, 0, stream>>>(pa);

    // --- dual GEMM (cat16, persistent 128², 2 blk/CU): delta/b ---
    gemm128p_kernel<0><<<512, 256, 0, stream>>>(
        y1, wcat_db, D_, D_, 16, delta_b, b_b, A_log, nullptr, ABp);

    // --- chunked fused liquid + PLIF scans ---
    scan_kernel<<<(B_ * SCAN_C * D_) / 256, 256, 0, stream>>>(ABp, log_tau, plif_thr, spikein);

    // --- dual GEMM (cat16): syn/gate -> x1 = x + syn*sigmoid(gate) ---
    gemm128p_kernel<1><<<512, 256, 0, stream>>>(
        spikein, wcat_sg, D_, D_, 16, syn_b, gate_b, x, nullptr, x1);

    // --- RMSNorm 2 (bf16 in) ---
    rmsnorm_bf_kernel<<<M_, 256, 0, stream>>>(x1, rms_w2, y2);

    // --- dual GEMM (cat16): ffn gate/up -> act = silu(g)*u ---
    gemm128p_kernel<2><<<512, 256, 0, stream>>>(
        y2, wcat_gu, D_, DFF_, 64, nullptr, nullptr, nullptr, nullptr, act);

    // --- GEMM: ffn down + residual -> out ---
    gemm128p_kernel<3><<<512, 256, 0, stream>>>(
        act, wd, DFF_, D_, 8, nullptr, nullptr, nullptr, x1, outF);
}

// Round 10
// 918.286 us; speedup vs baseline: 1.0793x; 1.0793x over previous
//
#include <hip/hip_runtime.h>
#include <stdint.h>

#define B_   8
#define T_   2048
#define D_   1024
#define DFF_ 4096
#define M_   (B_ * T_)   // 16384

typedef __bf16 bf16;
typedef bf16  bf16x8 __attribute__((ext_vector_type(8)));
typedef bf16  bf16x4 __attribute__((ext_vector_type(4)));
typedef float f32x4  __attribute__((ext_vector_type(4)));

#define CAST_LDS(p) ((__attribute__((address_space(3))) void*)(p))
#define CAST_GLB(p) ((const __attribute__((address_space(1))) void*)(p))

// ---------------------------------------------------------------------------
// Fused prep kernel: cat16 weight cvt (3 tensors) + plain cvt (ffn_d) +
// RMSNorm1 — all independent, one launch.  (unchanged, verified)
// ---------------------------------------------------------------------------
struct PrepArgs {
    const float* w1[3];
    const float* w2[3];
    bf16* dst[3];
    int end[3];            // {2048, 4096, 12288}
    const float* fd;       // ffn_d_w fp32
    bf16* fdd;             // -> wd
    const float* x;
    const float* rw1;
    bf16* y1;
};

__global__ __launch_bounds__(256) void prep_kernel(PrepArgs a) {
    __shared__ float red[4];
    const int blk = blockIdx.x;
    const int t = threadIdx.x;

    if (blk >= 16384) {   // ---- RMSNorm 1 (fp32 in -> bf16) ----
        const size_t row = blk - 16384;
        const float4 v = ((const float4*)(a.x + row * D_))[t];
        float ss = v.x * v.x + v.y * v.y + v.z * v.z + v.w * v.w;
#pragma unroll
        for (int off = 32; off; off >>= 1) ss += __shfl_down(ss, off);
        if ((t & 63) == 0) red[t >> 6] = ss;
        __syncthreads();
        const float total = red[0] + red[1] + red[2] + red[3];
        const float rstd = rsqrtf(total * (1.0f / (float)D_) + 1e-6f);
        const float4 wv = ((const float4*)a.rw1)[t];
        bf16x4 o;
        o[0] = (bf16)(v.x * rstd * wv.x);
        o[1] = (bf16)(v.y * rstd * wv.y);
        o[2] = (bf16)(v.z * rstd * wv.z);
        o[3] = (bf16)(v.w * rstd * wv.w);
        ((bf16x4*)(a.y1 + row * D_))[t] = o;
        return;
    }
    if (blk >= 12288) {   // ---- plain cvt: ffn_d ----
        const int i = ((blk - 12288) * 256 + t) * 4;
        const float4 v = *(const float4*)(a.fd + i);
        bf16x4 o;
        o[0] = (bf16)v.x; o[1] = (bf16)v.y; o[2] = (bf16)v.z; o[3] = (bf16)v.w;
        *(bf16x4*)(a.fdd + i) = o;
        return;
    }
    // ---- cat16 cvt ----
    const int seg = (blk >= a.end[0] ? 1 : 0) + (blk >= a.end[1] ? 1 : 0);
    const int d = blk - (seg ? a.end[seg - 1] : 0);
    const int rr = d & 31;
    const float* src = ((rr < 16) ? a.w1[seg] : a.w2[seg]) +
                       (size_t)(((d >> 5) << 4) + (d & 15)) * D_;
    bf16* dst = a.dst[seg] + (size_t)d * D_;
    const float4 v = ((const float4*)src)[t];
    bf16x4 o;
    o[0] = (bf16)v.x; o[1] = (bf16)v.y; o[2] = (bf16)v.z; o[3] = (bf16)v.w;
    ((bf16x4*)dst)[t] = o;
}

// ---------------------------------------------------------------------------
// RMSNorm bf16-in (x1 path) -> bf16 out   (unchanged, verified)
// ---------------------------------------------------------------------------
__global__ __launch_bounds__(256) void rmsnorm_bf_kernel(const bf16* __restrict__ x,
                                                         const float* __restrict__ w,
                                                         bf16* __restrict__ y) {
    const size_t row = blockIdx.x;
    const int t = threadIdx.x;
    const bf16x4 xv = ((const bf16x4*)(x + row * D_))[t];
    float f0 = (float)xv[0], f1 = (float)xv[1], f2 = (float)xv[2], f3 = (float)xv[3];
    float ss = f0 * f0 + f1 * f1 + f2 * f2 + f3 * f3;
#pragma unroll
    for (int off = 32; off; off >>= 1) ss += __shfl_down(ss, off);
    __shared__ float red[4];
    if ((t & 63) == 0) red[t >> 6] = ss;
    __syncthreads();
    const float total = red[0] + red[1] + red[2] + red[3];
    const float rstd = rsqrtf(total * (1.0f / (float)D_) + 1e-6f);
    const float4 wv = ((const float4*)w)[t];
    bf16x4 o;
    o[0] = (bf16)(f0 * rstd * wv.x);
    o[1] = (bf16)(f1 * rstd * wv.y);
    o[2] = (bf16)(f2 * rstd * wv.z);
    o[3] = (bf16)(f3 * rstd * wv.w);
    ((bf16x4*)(y + row * D_))[t] = o;
}

// ---------------------------------------------------------------------------
// Chunked fused liquid-tanh + PLIF scan.   (unchanged, verified)
// ---------------------------------------------------------------------------
#define SCAN_C  32
#define SCAN_L  (T_ / SCAN_C)   // 64
#define SCAN_W  32
#define SCAN_PF 8

template <int N, int W0>
__device__ __forceinline__ void scan_body(const uint32_t* __restrict__ p,
                                          bf16* __restrict__ o, const int ts,
                                          const float pdec, const float om,
                                          const float th) {
    uint32_t buf[SCAN_PF];
#pragma unroll
    for (int i = 0; i < SCAN_PF; ++i) buf[i] = p[(size_t)i * D_];
    float h = 0.0f, v = 0.0f;
#pragma unroll 8
    for (int k = 0; k < N; ++k) {
        const uint32_t w = buf[k & (SCAN_PF - 1)];
        if (k + SCAN_PF < N) buf[k & (SCAN_PF - 1)] = p[(size_t)(k + SCAN_PF) * D_];
        const float a  = __builtin_bit_cast(float, w << 16);
        const float bb = __builtin_bit_cast(float, w & 0xffff0000u);
        const float xv = fmaf(a, h, bb);
        const float e2 = __expf(2.0f * xv);
        h = 1.0f - __fdividef(2.0f, 1.0f + e2);          // tanh(xv)
        const float vpre = fmaf(pdec, v, om * h);
        const float s = (vpre > th) ? 1.0f : 0.0f;
        v = vpre - s * th;
        if (k >= W0) o[(size_t)(ts + k) * D_] = (bf16)(s + h);
    }
}

__global__ __launch_bounds__(256) void scan_kernel(const uint32_t* __restrict__ ABp,
                                                   const float* __restrict__ log_tau,
                                                   const float* __restrict__ thr,
                                                   bf16* __restrict__ sp) {
    const int g = blockIdx.x * 256 + threadIdx.x;
    const int d = g & (D_ - 1);
    const int bc = g >> 10;
    const int b = bc / SCAN_C;
    const int c = bc % SCAN_C;
    const float pdec = __expf(-__expf(-log_tau[d]));
    const float om = 1.0f - pdec;
    const float th = thr[d];
    const int t0 = c * SCAN_L;
    const uint32_t* base = ABp + (size_t)b * (T_ * D_) + d;
    bf16* o = sp + (size_t)b * (T_ * D_) + d;
    if (c == 0) {
        scan_body<SCAN_L, 0>(base, o, 0, pdec, om, th);
    } else {
        const int ts = t0 - SCAN_W;
        scan_body<SCAN_L + SCAN_W, SCAN_W>(base + (size_t)ts * D_, o, ts, pdec, om, th);
    }
}

// ---------------------------------------------------------------------------
// PERSISTENT 8-phase 256x256 GEMM (round-5/8 verified structure) +
// ROUND 10: sched_group_barrier pins DS_READ-before-MFMA in each phase.
// Theory: at the 256-reg limit the scheduler sinks the (independent)
// next-phase PREF ds_reads BELOW the MFMA cluster to shorten live ranges,
// serializing the DS pipe (~565cy) after the matrix pipe (~580cy) ->
// measured 1326 cy/phase = sum.  m201's identical logical schedule runs
// 828 cy/phase with the reads overlapped.  The SGB pair per phase
// (DS_READ group first, then 16 MFMA) forces emission order so the DS
// pipe services PREF during the MFMA window.  No sync-semantics change;
// accumulation order unchanged -> bit-identical output.
// SGB masks (per guide T19): DS_READ=0x100, MFMA=0x8.
// MODE 0: delta/b -> pack bf16(A_t)|bf16(b_t)<<16 (u32)
// MODE 1: syn/gate -> out = x + syn*sigmoid(gate) (bf16)
// MODE 2: ffn g/u -> out = silu(g)*u (bf16)
// MODE 3: ffn down (no cat) -> out = x1 + acc (fp32)
// ---------------------------------------------------------------------------

#define STG_A(kt, par, kh)                                                             \
  { bf16* l_ = lA0 + (((par) << 1) + (kh)) * 8192;                                     \
    const bf16* g_ = gA + (kt) * 64 + ((kh) << 5);                                     \
    __builtin_amdgcn_global_load_lds(CAST_GLB(g_), CAST_LDS(l_), 16, 0, 0);            \
    __builtin_amdgcn_global_load_lds(CAST_GLB(g_ + g2), CAST_LDS(l_ + 4096), 16, 0, 0); }
#define STG_B(gb, kt, par, kh)                                                         \
  { bf16* l_ = lB0 + (((par) << 1) + (kh)) * 8192;                                     \
    const bf16* g_ = (gb) + (kt) * 64 + ((kh) << 5);                                   \
    __builtin_amdgcn_global_load_lds(CAST_GLB(g_), CAST_LDS(l_), 16, 0, 0);            \
    __builtin_amdgcn_global_load_lds(CAST_GLB(g_ + g2), CAST_LDS(l_ + 4096), 16, 0, 0); }
#define PREF_A(dst, slot, MH)                                                          \
  { const bf16* As_ = smA + (slot) * 8192 + swz;                                       \
    _Pragma("unroll")                                                                  \
    for (int i = 0; i < 4; ++i)                                                        \
      dst[i] = *(const bf16x8*)(As_ + (mr128 + (MH) * 64 + i * 16 + lane15) * 32);     \
  }
#define PREF_B(dst, slot)                                                              \
  { const bf16* Bs_ = smB + (slot) * 8192 + swz;                                       \
    _Pragma("unroll")                                                                  \
    for (int j = 0; j < 4; ++j)                                                        \
      dst[j] = *(const bf16x8*)(Bs_ + (nc64 + j * 16 + lane15) * 32);                  \
  }
#define MFMA16(A_, B_, MH)                                                             \
  _Pragma("unroll")                                                                    \
  for (int i = 0; i < 4; ++i)                                                          \
    _Pragma("unroll")                                                                  \
    for (int j = 0; j < 4; ++j)                                                        \
      acc[(MH) * 4 + i][j] = __builtin_amdgcn_mfma_f32_16x16x32_bf16(                  \
          A_[i], B_[j], acc[(MH) * 4 + i][j], 0, 0, 0);
#define GBAR() __builtin_amdgcn_s_barrier()
#define LGKM0() asm volatile("s_waitcnt lgkmcnt(0)" ::: "memory")
// T19 pin: emit NDS ds_reads first, then 16 MFMAs, within this region.
#define SGB_DS_MFMA(NDS)                                                               \
  __builtin_amdgcn_sched_group_barrier(0x100, (NDS), 0);                               \
  __builtin_amdgcn_sched_group_barrier(0x8, 16, 0);

template <int MODE>
__global__ __launch_bounds__(512, 2) void gemm8p_kernel(
    const bf16* __restrict__ A, const bf16* __restrict__ Bw,
    const int K, const int Nlog, const int NTN,
    const float* __restrict__ b1, const float* __restrict__ b2,
    const float* __restrict__ extra, const bf16* __restrict__ extra_bf,
    void* __restrict__ outp) {
    __shared__ bf16 smem[65536] __attribute__((aligned(16)));   // 128 KiB
    bf16* const smA = smem;             // 4 slots x 8192 elems ([256][32] each)
    bf16* const smB = smem + 32768;

    const int tid = threadIdx.x;
    const int wave = tid >> 6;
    const int lane = tid & 63;
    const int lane15 = lane & 15;
    const int quad = lane >> 4;
    const int mr = wave >> 2;          // 0..1
    const int nc = wave & 3;           // 0..3
    const int mr128 = mr * 128;
    const int nc64 = nc * 64;
    const int swz = (quad ^ ((lane15 >> 1) & 3)) << 3;   // constant per lane

    const int xcd = blockIdx.x & 7;
    const int cu  = blockIdx.x >> 3;    // 0..31
    const int mt  = xcd * 8 + (cu & 7); // fixed per block
    const int nt0 = cu >> 3;            // 0..3
    const int TPB = NTN >> 2;
    const int NT  = K >> 6;
    const int S   = TPB * NT;

    const int srow = tid >> 2;                               // 0..127 (q=0)
    const int scol = (((tid & 3) ^ ((srow >> 1) & 3)) << 3); // pre-swizzled col
    const bf16* const gA = A + (size_t)(mt * 256 + srow) * K + scol;
    const size_t g2 = (size_t)128 * K;                       // q=1: rows +128
    const size_t dB = (size_t)1024 * K;                      // nt += 4 per tile
    const bf16* gBc = Bw + (size_t)(nt0 * 256 + srow) * K + scol;
    bf16* const lA0 = smA + (wave << 9);
    bf16* const lB0 = smB + (wave << 9);

    f32x4 acc[8][4] = {};
    bf16x8 a0[4], a1[4], b0[4], b1_[4];

    // prologue: step 0 fully + 3 half-tiles of step 1 (steady pattern)
    STG_B(gBc, 0, 0, 0); STG_A(0, 0, 0); STG_B(gBc, 0, 0, 1); STG_A(0, 0, 1);
    asm volatile("s_waitcnt vmcnt(4)" ::: "memory");
    STG_B(gBc, 1, 1, 0); STG_A(1, 1, 0); STG_B(gBc, 1, 1, 1);
    asm volatile("s_waitcnt vmcnt(6)" ::: "memory");
    GBAR();
    // initial fragment fill for P1 of step 0 (slot 0)
    PREF_A(a0, 0, 0);
    PREF_B(b0, 0);

    for (int w = 0; w < TPB; ++w) {
        const bf16* const gBn = gBc + dB;   // next tile's B base
        for (int t = 0; t < NT; ++t) {
            const int s = w * NT + t;
            const int cb = (t & 1) << 1;                         // this step's slots
            const int nb = cb ^ 2;                               // next step's slots
            const int tp1 = (t + 1 == NT) ? 0 : t + 1;           // kt of s+1
            const int tp2 = (t + 2 >= NT) ? t + 2 - NT : t + 2;  // kt of s+2
            const int par1 = (t + 1) & 1;                        // parity of s+1
            const int par2 = t & 1;                              // parity of s+2
            const bf16* const gB2 = (t + 2 >= NT) ? gBn : gBc;
            const bool st1 = (s + 1 < S);
            const bool st2 = (s + 2 < S);

            // phase 1: MFMA(k0,MH0) using a0,b0; prefetch a1 <- A[k0,MH1]
            if (st1) STG_A(tp1, par1, 1);
            GBAR(); LGKM0();
            __builtin_amdgcn_s_setprio(1);
            PREF_A(a1, cb + 0, 1);
            MFMA16(a0, b0, 0);
            SGB_DS_MFMA(4);
            __builtin_amdgcn_s_setprio(0);
            GBAR();

            // phase 2: MFMA(k0,MH1) using a1,b0; prefetch a0 <- A[k1,MH0], b1 <- B[k1]
            if (st2) STG_B(gB2, tp2, par2, 0);
            GBAR(); LGKM0();
            __builtin_amdgcn_s_setprio(1);
            PREF_A(a0, cb + 1, 0);
            PREF_B(b1_, cb + 1);
            MFMA16(a1, b0, 1);
            SGB_DS_MFMA(8);
            __builtin_amdgcn_s_setprio(0);
            GBAR();

            // phase 3: MFMA(k1,MH0) using a0,b1; prefetch a1 <- A[k1,MH1]
            if (st2) STG_A(tp2, par2, 0);
            GBAR(); LGKM0();
            __builtin_amdgcn_s_setprio(1);
            PREF_A(a1, cb + 1, 1);
            MFMA16(a0, b1_, 0);
            SGB_DS_MFMA(4);
            __builtin_amdgcn_s_setprio(0);
            GBAR();

            // phase 4: MFMA(k1,MH1) using a1,b1; prefetch a0,b0 <- next step k0
            if (st2) {
                STG_B(gB2, tp2, par2, 1);
                asm volatile("s_waitcnt vmcnt(6)" ::: "memory");
            } else {
                asm volatile("s_waitcnt vmcnt(0)" ::: "memory");
            }
            GBAR(); LGKM0();
            __builtin_amdgcn_s_setprio(1);
            PREF_A(a0, nb + 0, 0);
            PREF_B(b0, nb + 0);
            MFMA16(a1, b1_, 1);
            SGB_DS_MFMA(8);
            __builtin_amdgcn_s_setprio(0);
            GBAR();
        }

        // ---- per-tile epilogue (register-local; LDS untouched, pipeline warm)
        if constexpr (MODE != 3) {
            const int nlog0 = (nt0 + w * 4) * 128 + nc * 32;
            const int mbase = mt * 256 + mr128;
#pragma unroll
            for (int i8 = 0; i8 < 8; ++i8)
#pragma unroll
                for (int jp = 0; jp < 2; ++jp)
#pragma unroll
                    for (int r = 0; r < 4; ++r) {
                        const int m = mbase + i8 * 16 + quad * 4 + r;
                        const int n = nlog0 + jp * 16 + lane15;
                        const size_t idx = (size_t)m * Nlog + n;
                        const float v1 = acc[i8][jp * 2][r];      // W1 side
                        const float v2 = acc[i8][jp * 2 + 1][r];  // W2 side
                        if constexpr (MODE == 0) {
                            const float dl = v1 + b1[n];
                            const float spv = (dl > 20.0f) ? dl : log1pf(__expf(dl));
                            const float bv = spv * (v2 + b2[n]);
                            const float av = __expf(-spv * __expf(extra[n]));
                            const uint32_t pa =
                                (uint32_t)__builtin_bit_cast(unsigned short, (bf16)av);
                            const uint32_t pb =
                                (uint32_t)__builtin_bit_cast(unsigned short, (bf16)bv);
                            ((uint32_t*)outp)[idx] = pa | (pb << 16);
                        } else if constexpr (MODE == 1) {
                            const float syn = v1 + b1[n];
                            const float z = v2 + b2[n];
                            const float gate = 1.0f / (1.0f + __expf(-z));
                            ((bf16*)outp)[idx] = (bf16)(extra[idx] + syn * gate);
                        } else {   // MODE 2
                            const float sg = v1 / (1.0f + __expf(-v1));
                            ((bf16*)outp)[idx] = (bf16)(sg * v2);
                        }
                    }
        } else {   // MODE 3: single-B, direct fp32 write
            const int mbase = mt * 256 + mr128;
            const int nbase = (nt0 + w * 4) * 256 + nc64;
#pragma unroll
            for (int i8 = 0; i8 < 8; ++i8)
#pragma unroll
                for (int j = 0; j < 4; ++j)
#pragma unroll
                    for (int r = 0; r < 4; ++r) {
                        const int m = mbase + i8 * 16 + quad * 4 + r;
                        const int n = nbase + j * 16 + lane15;
                        const size_t idx = (size_t)m * Nlog + n;
                        ((float*)outp)[idx] = (float)extra_bf[idx] + acc[i8][j][r];
                    }
        }

        if (w + 1 < TPB) {
#pragma unroll
            for (int i8 = 0; i8 < 8; ++i8)
#pragma unroll
                for (int j = 0; j < 4; ++j)
                    acc[i8][j] = (f32x4){0.0f, 0.0f, 0.0f, 0.0f};
            gBc = gBn;
        }
    }
}

#undef STG_A
#undef STG_B
#undef PREF_A
#undef PREF_B
#undef MFMA16
#undef SGB_DS_MFMA
#undef GBAR
#undef LGKM0

// ---------------------------------------------------------------------------
extern "C" void kernel_launch(void* const* d_in, const int* in_sizes, int n_in,
                              void* d_out, int out_size, void* d_ws, size_t ws_size,
                              hipStream_t stream) {
    const float* x        = (const float*)d_in[0];
    const float* rms_w1   = (const float*)d_in[1];
    const float* rms_w2   = (const float*)d_in[2];
    const float* delta_w  = (const float*)d_in[3];
    const float* delta_b  = (const float*)d_in[4];
    const float* b_w      = (const float*)d_in[5];
    const float* b_b      = (const float*)d_in[6];
    const float* A_log    = (const float*)d_in[7];
    const float* log_tau  = (const float*)d_in[8];
    const float* plif_thr = (const float*)d_in[9];
    const float* syn_w    = (const float*)d_in[10];
    const float* syn_b    = (const float*)d_in[11];
    const float* gate_w   = (const float*)d_in[12];
    const float* gate_b   = (const float*)d_in[13];
    const float* ffn_g_w  = (const float*)d_in[14];
    const float* ffn_u_w  = (const float*)d_in[15];
    const float* ffn_d_w  = (const float*)d_in[16];

    char* ws = (char*)d_ws;
    const size_t MB = 1024ull * 1024ull;
    // cat16-interleaved bf16 weights: [0,32MB)
    bf16* wcat_db = (bf16*)(ws + 0 * MB);    // [2048,1024]  4MB
    bf16* wcat_sg = (bf16*)(ws + 4 * MB);    // [2048,1024]  4MB
    bf16* wcat_gu = (bf16*)(ws + 8 * MB);    // [8192,1024] 16MB
    bf16* wd      = (bf16*)(ws + 24 * MB);   // [1024,4096]  8MB
    // phase-1 buffers (all dead before act is written):
    bf16*     y1      = (bf16*)(ws + 32 * MB);       // 32MB
    uint32_t* ABp     = (uint32_t*)(ws + 64 * MB);   // 64MB
    bf16*     spikein = (bf16*)(ws + 128 * MB);      // 32MB
    // persistent:
    bf16* x1 = (bf16*)(ws + 160 * MB);               // 32MB (bf16)
    bf16* y2 = (bf16*)(ws + 224 * MB);               // 32MB
    // act aliases the dead phase-1 region [32MB,160MB): 16384*4096*2 = 128MB
    bf16* act = (bf16*)(ws + 32 * MB);
    float* outF = (float*)d_out;

    // --- fused prep: weight converts + RMSNorm 1 (one launch) ---
    PrepArgs pa;
    pa.w1[0] = delta_w; pa.w2[0] = b_w;     pa.dst[0] = wcat_db;
    pa.w1[1] = syn_w;   pa.w2[1] = gate_w;  pa.dst[1] = wcat_sg;
    pa.w1[2] = ffn_g_w; pa.w2[2] = ffn_u_w; pa.dst[2] = wcat_gu;
    pa.end[0] = 2048; pa.end[1] = 4096; pa.end[2] = 12288;
    pa.fd = ffn_d_w; pa.fdd = wd;
    pa.x = x; pa.rw1 = rms_w1; pa.y1 = y1;
    prep_kernel<<<32768, 256, 0, stream>>>(pa);

    // --- dual GEMM (cat16, persistent): delta/b -> packed (A_t, b_t) ---
    gemm8p_kernel<0><<<256, 512, 0, stream>>>(
        y1, wcat_db, D_, D_, 8, delta_b, b_b, A_log, nullptr, ABp);

    // --- chunked fused liquid + PLIF scans ---
    scan_kernel<<<(B_ * SCAN_C * D_) / 256, 256, 0, stream>>>(ABp, log_tau, plif_thr, spikein);

    // --- dual GEMM (cat16, persistent): syn/gate -> x1 = x + syn*sigmoid(gate) ---
    gemm8p_kernel<1><<<256, 512, 0, stream>>>(
        spikein, wcat_sg, D_, D_, 8, syn_b, gate_b, x, nullptr, x1);

    // --- RMSNorm 2 (bf16 in) ---
    rmsnorm_bf_kernel<<<M_, 256, 0, stream>>>(x1, rms_w2, y2);

    // --- dual GEMM (cat16, persistent): ffn gate/up -> act = silu(g)*u ---
    gemm8p_kernel<2><<<256, 512, 0, stream>>>(
        y2, wcat_gu, D_, DFF_, 32, nullptr, nullptr, nullptr, nullptr, act);

    // --- GEMM (persistent, TPB=1): ffn down + residual -> out ---
    gemm8p_kernel<3><<<256, 512, 0, stream>>>(
        act, wd, DFF_, D_, 4, nullptr, nullptr, nullptr, x1, outF);
}

// Round 11
// 882.228 us; speedup vs baseline: 1.1234x; 1.0409x over previous
//
#include <hip/hip_runtime.h>
#include <stdint.h>

#define B_   8
#define T_   2048
#define D_   1024
#define DFF_ 4096
#define M_   (B_ * T_)   // 16384

typedef __bf16 bf16;
typedef bf16  bf16x8 __attribute__((ext_vector_type(8)));
typedef bf16  bf16x4 __attribute__((ext_vector_type(4)));
typedef float f32x4  __attribute__((ext_vector_type(4)));

#define CAST_LDS(p) ((__attribute__((address_space(3))) void*)(p))
#define CAST_GLB(p) ((const __attribute__((address_space(1))) void*)(p))

// ---------------------------------------------------------------------------
// Fused prep kernel: cat16 weight cvt (3 tensors) + plain cvt (ffn_d) +
// RMSNorm1 — all independent, one launch.  (verified)
// ---------------------------------------------------------------------------
struct PrepArgs {
    const float* w1[3];
    const float* w2[3];
    bf16* dst[3];
    int end[3];            // {2048, 4096, 12288}
    const float* fd;       // ffn_d_w fp32
    bf16* fdd;             // -> wd
    const float* x;
    const float* rw1;
    bf16* y1;
};

__global__ __launch_bounds__(256) void prep_kernel(PrepArgs a) {
    __shared__ float red[4];
    const int blk = blockIdx.x;
    const int t = threadIdx.x;

    if (blk >= 16384) {   // ---- RMSNorm 1 (fp32 in -> bf16) ----
        const size_t row = blk - 16384;
        const float4 v = ((const float4*)(a.x + row * D_))[t];
        float ss = v.x * v.x + v.y * v.y + v.z * v.z + v.w * v.w;
#pragma unroll
        for (int off = 32; off; off >>= 1) ss += __shfl_down(ss, off);
        if ((t & 63) == 0) red[t >> 6] = ss;
        __syncthreads();
        const float total = red[0] + red[1] + red[2] + red[3];
        const float rstd = rsqrtf(total * (1.0f / (float)D_) + 1e-6f);
        const float4 wv = ((const float4*)a.rw1)[t];
        bf16x4 o;
        o[0] = (bf16)(v.x * rstd * wv.x);
        o[1] = (bf16)(v.y * rstd * wv.y);
        o[2] = (bf16)(v.z * rstd * wv.z);
        o[3] = (bf16)(v.w * rstd * wv.w);
        ((bf16x4*)(a.y1 + row * D_))[t] = o;
        return;
    }
    if (blk >= 12288) {   // ---- plain cvt: ffn_d ----
        const int i = ((blk - 12288) * 256 + t) * 4;
        const float4 v = *(const float4*)(a.fd + i);
        bf16x4 o;
        o[0] = (bf16)v.x; o[1] = (bf16)v.y; o[2] = (bf16)v.z; o[3] = (bf16)v.w;
        *(bf16x4*)(a.fdd + i) = o;
        return;
    }
    // ---- cat16 cvt ----
    const int seg = (blk >= a.end[0] ? 1 : 0) + (blk >= a.end[1] ? 1 : 0);
    const int d = blk - (seg ? a.end[seg - 1] : 0);
    const int rr = d & 31;
    const float* src = ((rr < 16) ? a.w1[seg] : a.w2[seg]) +
                       (size_t)(((d >> 5) << 4) + (d & 15)) * D_;
    bf16* dst = a.dst[seg] + (size_t)d * D_;
    const float4 v = ((const float4*)src)[t];
    bf16x4 o;
    o[0] = (bf16)v.x; o[1] = (bf16)v.y; o[2] = (bf16)v.z; o[3] = (bf16)v.w;
    ((bf16x4*)dst)[t] = o;
}

// ---------------------------------------------------------------------------
// RMSNorm bf16-in (x1 path) -> bf16 out   (verified)
// ---------------------------------------------------------------------------
__global__ __launch_bounds__(256) void rmsnorm_bf_kernel(const bf16* __restrict__ x,
                                                         const float* __restrict__ w,
                                                         bf16* __restrict__ y) {
    const size_t row = blockIdx.x;
    const int t = threadIdx.x;
    const bf16x4 xv = ((const bf16x4*)(x + row * D_))[t];
    float f0 = (float)xv[0], f1 = (float)xv[1], f2 = (float)xv[2], f3 = (float)xv[3];
    float ss = f0 * f0 + f1 * f1 + f2 * f2 + f3 * f3;
#pragma unroll
    for (int off = 32; off; off >>= 1) ss += __shfl_down(ss, off);
    __shared__ float red[4];
    if ((t & 63) == 0) red[t >> 6] = ss;
    __syncthreads();
    const float total = red[0] + red[1] + red[2] + red[3];
    const float rstd = rsqrtf(total * (1.0f / (float)D_) + 1e-6f);
    const float4 wv = ((const float4*)w)[t];
    bf16x4 o;
    o[0] = (bf16)(f0 * rstd * wv.x);
    o[1] = (bf16)(f1 * rstd * wv.y);
    o[2] = (bf16)(f2 * rstd * wv.z);
    o[3] = (bf16)(f3 * rstd * wv.w);
    ((bf16x4*)(y + row * D_))[t] = o;
}

// ---------------------------------------------------------------------------
// Chunked fused liquid-tanh + PLIF scan.   (verified)
// ---------------------------------------------------------------------------
#define SCAN_C  32
#define SCAN_L  (T_ / SCAN_C)   // 64
#define SCAN_W  32
#define SCAN_PF 8

template <int N, int W0>
__device__ __forceinline__ void scan_body(const uint32_t* __restrict__ p,
                                          bf16* __restrict__ o, const int ts,
                                          const float pdec, const float om,
                                          const float th) {
    uint32_t buf[SCAN_PF];
#pragma unroll
    for (int i = 0; i < SCAN_PF; ++i) buf[i] = p[(size_t)i * D_];
    float h = 0.0f, v = 0.0f;
#pragma unroll 8
    for (int k = 0; k < N; ++k) {
        const uint32_t w = buf[k & (SCAN_PF - 1)];
        if (k + SCAN_PF < N) buf[k & (SCAN_PF - 1)] = p[(size_t)(k + SCAN_PF) * D_];
        const float a  = __builtin_bit_cast(float, w << 16);
        const float bb = __builtin_bit_cast(float, w & 0xffff0000u);
        const float xv = fmaf(a, h, bb);
        const float e2 = __expf(2.0f * xv);
        h = 1.0f - __fdividef(2.0f, 1.0f + e2);          // tanh(xv)
        const float vpre = fmaf(pdec, v, om * h);
        const float s = (vpre > th) ? 1.0f : 0.0f;
        v = vpre - s * th;
        if (k >= W0) o[(size_t)(ts + k) * D_] = (bf16)(s + h);
    }
}

__global__ __launch_bounds__(256) void scan_kernel(const uint32_t* __restrict__ ABp,
                                                   const float* __restrict__ log_tau,
                                                   const float* __restrict__ thr,
                                                   bf16* __restrict__ sp) {
    const int g = blockIdx.x * 256 + threadIdx.x;
    const int d = g & (D_ - 1);
    const int bc = g >> 10;
    const int b = bc / SCAN_C;
    const int c = bc % SCAN_C;
    const float pdec = __expf(-__expf(-log_tau[d]));
    const float om = 1.0f - pdec;
    const float th = thr[d];
    const int t0 = c * SCAN_L;
    const uint32_t* base = ABp + (size_t)b * (T_ * D_) + d;
    bf16* o = sp + (size_t)b * (T_ * D_) + d;
    if (c == 0) {
        scan_body<SCAN_L, 0>(base, o, 0, pdec, om, th);
    } else {
        const int ts = t0 - SCAN_W;
        scan_body<SCAN_L + SCAN_W, SCAN_W>(base + (size_t)ts * D_, o, ts, pdec, om, th);
    }
}

// ---------------------------------------------------------------------------
// PERSISTENT 8-phase 256x256 GEMM with FRAGMENT PING-PONG — round-5/8
// verified configuration, restored VERBATIM (880.5 / 891.6 µs total across
// two runs; g/u 283 µs / 938 TF; VGPR 128 + AGPR 128 = exactly the 256-reg
// budget; bank conflicts 0; no scratch).
// CEILING NOTES (three independent confirmations): any perturbation of
// this loop's code shape at the 256-reg boundary spills to scratch —
//   r6 single-barrier reorder  -> FETCH +190MB, 22% MfmaUtil
//   r7 unroll-2 static slots   -> FETCH +140MB, 35% MfmaUtil
//   r10 sched_group_barrier    -> FETCH  +33MB, 38% MfmaUtil
// and r9's 128²/2-block occupancy trade halves arithmetic intensity
// (FETCH 2x, 34%).  Do not re-attempt these.
// MODE 0: delta/b -> pack bf16(A_t)|bf16(b_t)<<16 (u32)
// MODE 1: syn/gate -> out = x + syn*sigmoid(gate) (bf16)
// MODE 2: ffn g/u -> out = silu(g)*u (bf16)
// MODE 3: ffn down (no cat) -> out = x1 + acc (fp32)
// ---------------------------------------------------------------------------

#define STG_A(kt, par, kh)                                                             \
  { bf16* l_ = lA0 + (((par) << 1) + (kh)) * 8192;                                     \
    const bf16* g_ = gA + (kt) * 64 + ((kh) << 5);                                     \
    __builtin_amdgcn_global_load_lds(CAST_GLB(g_), CAST_LDS(l_), 16, 0, 0);            \
    __builtin_amdgcn_global_load_lds(CAST_GLB(g_ + g2), CAST_LDS(l_ + 4096), 16, 0, 0); }
#define STG_B(gb, kt, par, kh)                                                         \
  { bf16* l_ = lB0 + (((par) << 1) + (kh)) * 8192;                                     \
    const bf16* g_ = (gb) + (kt) * 64 + ((kh) << 5);                                   \
    __builtin_amdgcn_global_load_lds(CAST_GLB(g_), CAST_LDS(l_), 16, 0, 0);            \
    __builtin_amdgcn_global_load_lds(CAST_GLB(g_ + g2), CAST_LDS(l_ + 4096), 16, 0, 0); }
#define PREF_A(dst, slot, MH)                                                          \
  { const bf16* As_ = smA + (slot) * 8192 + swz;                                       \
    _Pragma("unroll")                                                                  \
    for (int i = 0; i < 4; ++i)                                                        \
      dst[i] = *(const bf16x8*)(As_ + (mr128 + (MH) * 64 + i * 16 + lane15) * 32);     \
  }
#define PREF_B(dst, slot)                                                              \
  { const bf16* Bs_ = smB + (slot) * 8192 + swz;                                       \
    _Pragma("unroll")                                                                  \
    for (int j = 0; j < 4; ++j)                                                        \
      dst[j] = *(const bf16x8*)(Bs_ + (nc64 + j * 16 + lane15) * 32);                  \
  }
#define MFMA16(A_, B_, MH)                                                             \
  _Pragma("unroll")                                                                    \
  for (int i = 0; i < 4; ++i)                                                          \
    _Pragma("unroll")                                                                  \
    for (int j = 0; j < 4; ++j)                                                        \
      acc[(MH) * 4 + i][j] = __builtin_amdgcn_mfma_f32_16x16x32_bf16(                  \
          A_[i], B_[j], acc[(MH) * 4 + i][j], 0, 0, 0);
#define GBAR() __builtin_amdgcn_s_barrier()
#define LGKM0() asm volatile("s_waitcnt lgkmcnt(0)" ::: "memory")

template <int MODE>
__global__ __launch_bounds__(512, 2) void gemm8p_kernel(
    const bf16* __restrict__ A, const bf16* __restrict__ Bw,
    const int K, const int Nlog, const int NTN,
    const float* __restrict__ b1, const float* __restrict__ b2,
    const float* __restrict__ extra, const bf16* __restrict__ extra_bf,
    void* __restrict__ outp) {
    __shared__ bf16 smem[65536] __attribute__((aligned(16)));   // 128 KiB
    bf16* const smA = smem;             // 4 slots x 8192 elems ([256][32] each)
    bf16* const smB = smem + 32768;

    const int tid = threadIdx.x;
    const int wave = tid >> 6;
    const int lane = tid & 63;
    const int lane15 = lane & 15;
    const int quad = lane >> 4;
    const int mr = wave >> 2;          // 0..1
    const int nc = wave & 3;           // 0..3
    const int mr128 = mr * 128;
    const int nc64 = nc * 64;
    const int swz = (quad ^ ((lane15 >> 1) & 3)) << 3;   // constant per lane

    const int xcd = blockIdx.x & 7;
    const int cu  = blockIdx.x >> 3;    // 0..31
    const int mt  = xcd * 8 + (cu & 7); // fixed per block
    const int nt0 = cu >> 3;            // 0..3
    const int TPB = NTN >> 2;
    const int NT  = K >> 6;
    const int S   = TPB * NT;

    const int srow = tid >> 2;                               // 0..127 (q=0)
    const int scol = (((tid & 3) ^ ((srow >> 1) & 3)) << 3); // pre-swizzled col
    const bf16* const gA = A + (size_t)(mt * 256 + srow) * K + scol;
    const size_t g2 = (size_t)128 * K;                       // q=1: rows +128
    const size_t dB = (size_t)1024 * K;                      // nt += 4 per tile
    const bf16* gBc = Bw + (size_t)(nt0 * 256 + srow) * K + scol;
    bf16* const lA0 = smA + (wave << 9);
    bf16* const lB0 = smB + (wave << 9);

    f32x4 acc[8][4] = {};
    bf16x8 a0[4], a1[4], b0[4], b1_[4];

    // prologue: step 0 fully + 3 half-tiles of step 1 (steady pattern)
    STG_B(gBc, 0, 0, 0); STG_A(0, 0, 0); STG_B(gBc, 0, 0, 1); STG_A(0, 0, 1);
    asm volatile("s_waitcnt vmcnt(4)" ::: "memory");
    STG_B(gBc, 1, 1, 0); STG_A(1, 1, 0); STG_B(gBc, 1, 1, 1);
    asm volatile("s_waitcnt vmcnt(6)" ::: "memory");
    GBAR();
    // initial fragment fill for P1 of step 0 (slot 0)
    PREF_A(a0, 0, 0);
    PREF_B(b0, 0);

    for (int w = 0; w < TPB; ++w) {
        const bf16* const gBn = gBc + dB;   // next tile's B base
        for (int t = 0; t < NT; ++t) {
            const int s = w * NT + t;
            const int cb = (t & 1) << 1;                         // this step's slots
            const int nb = cb ^ 2;                               // next step's slots
            const int tp1 = (t + 1 == NT) ? 0 : t + 1;           // kt of s+1
            const int tp2 = (t + 2 >= NT) ? t + 2 - NT : t + 2;  // kt of s+2
            const int par1 = (t + 1) & 1;                        // parity of s+1
            const int par2 = t & 1;                              // parity of s+2
            const bf16* const gB2 = (t + 2 >= NT) ? gBn : gBc;
            const bool st1 = (s + 1 < S);
            const bool st2 = (s + 2 < S);

            // phase 1: MFMA(k0,MH0) using a0,b0; prefetch a1 <- A[k0,MH1]
            if (st1) STG_A(tp1, par1, 1);
            GBAR(); LGKM0();
            __builtin_amdgcn_s_setprio(1);
            PREF_A(a1, cb + 0, 1);
            MFMA16(a0, b0, 0);
            __builtin_amdgcn_s_setprio(0);
            GBAR();

            // phase 2: MFMA(k0,MH1) using a1,b0; prefetch a0 <- A[k1,MH0], b1 <- B[k1]
            if (st2) STG_B(gB2, tp2, par2, 0);
            GBAR(); LGKM0();
            __builtin_amdgcn_s_setprio(1);
            PREF_A(a0, cb + 1, 0);
            PREF_B(b1_, cb + 1);
            MFMA16(a1, b0, 1);
            __builtin_amdgcn_s_setprio(0);
            GBAR();

            // phase 3: MFMA(k1,MH0) using a0,b1; prefetch a1 <- A[k1,MH1]
            if (st2) STG_A(tp2, par2, 0);
            GBAR(); LGKM0();
            __builtin_amdgcn_s_setprio(1);
            PREF_A(a1, cb + 1, 1);
            MFMA16(a0, b1_, 0);
            __builtin_amdgcn_s_setprio(0);
            GBAR();

            // phase 4: MFMA(k1,MH1) using a1,b1; prefetch a0,b0 <- next step k0
            if (st2) {
                STG_B(gB2, tp2, par2, 1);
                asm volatile("s_waitcnt vmcnt(6)" ::: "memory");
            } else {
                asm volatile("s_waitcnt vmcnt(0)" ::: "memory");
            }
            GBAR(); LGKM0();
            __builtin_amdgcn_s_setprio(1);
            PREF_A(a0, nb + 0, 0);
            PREF_B(b0, nb + 0);
            MFMA16(a1, b1_, 1);
            __builtin_amdgcn_s_setprio(0);
            GBAR();
        }

        // ---- per-tile epilogue (register-local; LDS untouched, pipeline warm)
        if constexpr (MODE != 3) {
            const int nlog0 = (nt0 + w * 4) * 128 + nc * 32;
            const int mbase = mt * 256 + mr128;
#pragma unroll
            for (int i8 = 0; i8 < 8; ++i8)
#pragma unroll
                for (int jp = 0; jp < 2; ++jp)
#pragma unroll
                    for (int r = 0; r < 4; ++r) {
                        const int m = mbase + i8 * 16 + quad * 4 + r;
                        const int n = nlog0 + jp * 16 + lane15;
                        const size_t idx = (size_t)m * Nlog + n;
                        const float v1 = acc[i8][jp * 2][r];      // W1 side
                        const float v2 = acc[i8][jp * 2 + 1][r];  // W2 side
                        if constexpr (MODE == 0) {
                            const float dl = v1 + b1[n];
                            const float spv = (dl > 20.0f) ? dl : log1pf(__expf(dl));
                            const float bv = spv * (v2 + b2[n]);
                            const float av = __expf(-spv * __expf(extra[n]));
                            const uint32_t pa =
                                (uint32_t)__builtin_bit_cast(unsigned short, (bf16)av);
                            const uint32_t pb =
                                (uint32_t)__builtin_bit_cast(unsigned short, (bf16)bv);
                            ((uint32_t*)outp)[idx] = pa | (pb << 16);
                        } else if constexpr (MODE == 1) {
                            const float syn = v1 + b1[n];
                            const float z = v2 + b2[n];
                            const float gate = 1.0f / (1.0f + __expf(-z));
                            ((bf16*)outp)[idx] = (bf16)(extra[idx] + syn * gate);
                        } else {   // MODE 2
                            const float sg = v1 / (1.0f + __expf(-v1));
                            ((bf16*)outp)[idx] = (bf16)(sg * v2);
                        }
                    }
        } else {   // MODE 3: single-B, direct fp32 write
            const int mbase = mt * 256 + mr128;
            const int nbase = (nt0 + w * 4) * 256 + nc64;
#pragma unroll
            for (int i8 = 0; i8 < 8; ++i8)
#pragma unroll
                for (int j = 0; j < 4; ++j)
#pragma unroll
                    for (int r = 0; r < 4; ++r) {
                        const int m = mbase + i8 * 16 + quad * 4 + r;
                        const int n = nbase + j * 16 + lane15;
                        const size_t idx = (size_t)m * Nlog + n;
                        ((float*)outp)[idx] = (float)extra_bf[idx] + acc[i8][j][r];
                    }
        }

        if (w + 1 < TPB) {
#pragma unroll
            for (int i8 = 0; i8 < 8; ++i8)
#pragma unroll
                for (int j = 0; j < 4; ++j)
                    acc[i8][j] = (f32x4){0.0f, 0.0f, 0.0f, 0.0f};
            gBc = gBn;
        }
    }
}

#undef STG_A
#undef STG_B
#undef PREF_A
#undef PREF_B
#undef MFMA16
#undef GBAR
#undef LGKM0

// ---------------------------------------------------------------------------
extern "C" void kernel_launch(void* const* d_in, const int* in_sizes, int n_in,
                              void* d_out, int out_size, void* d_ws, size_t ws_size,
                              hipStream_t stream) {
    const float* x        = (const float*)d_in[0];
    const float* rms_w1   = (const float*)d_in[1];
    const float* rms_w2   = (const float*)d_in[2];
    const float* delta_w  = (const float*)d_in[3];
    const float* delta_b  = (const float*)d_in[4];
    const float* b_w      = (const float*)d_in[5];
    const float* b_b      = (const float*)d_in[6];
    const float* A_log    = (const float*)d_in[7];
    const float* log_tau  = (const float*)d_in[8];
    const float* plif_thr = (const float*)d_in[9];
    const float* syn_w    = (const float*)d_in[10];
    const float* syn_b    = (const float*)d_in[11];
    const float* gate_w   = (const float*)d_in[12];
    const float* gate_b   = (const float*)d_in[13];
    const float* ffn_g_w  = (const float*)d_in[14];
    const float* ffn_u_w  = (const float*)d_in[15];
    const float* ffn_d_w  = (const float*)d_in[16];

    char* ws = (char*)d_ws;
    const size_t MB = 1024ull * 1024ull;
    // cat16-interleaved bf16 weights: [0,32MB)
    bf16* wcat_db = (bf16*)(ws + 0 * MB);    // [2048,1024]  4MB
    bf16* wcat_sg = (bf16*)(ws + 4 * MB);    // [2048,1024]  4MB
    bf16* wcat_gu = (bf16*)(ws + 8 * MB);    // [8192,1024] 16MB
    bf16* wd      = (bf16*)(ws + 24 * MB);   // [1024,4096]  8MB
    // phase-1 buffers (all dead before act is written):
    bf16*     y1      = (bf16*)(ws + 32 * MB);       // 32MB
    uint32_t* ABp     = (uint32_t*)(ws + 64 * MB);   // 64MB
    bf16*     spikein = (bf16*)(ws + 128 * MB);      // 32MB
    // persistent:
    bf16* x1 = (bf16*)(ws + 160 * MB);               // 32MB (bf16)
    bf16* y2 = (bf16*)(ws + 224 * MB);               // 32MB
    // act aliases the dead phase-1 region [32MB,160MB): 16384*4096*2 = 128MB
    bf16* act = (bf16*)(ws + 32 * MB);
    float* outF = (float*)d_out;

    // --- fused prep: weight converts + RMSNorm 1 (one launch) ---
    PrepArgs pa;
    pa.w1[0] = delta_w; pa.w2[0] = b_w;     pa.dst[0] = wcat_db;
    pa.w1[1] = syn_w;   pa.w2[1] = gate_w;  pa.dst[1] = wcat_sg;
    pa.w1[2] = ffn_g_w; pa.w2[2] = ffn_u_w; pa.dst[2] = wcat_gu;
    pa.end[0] = 2048; pa.end[1] = 4096; pa.end[2] = 12288;
    pa.fd = ffn_d_w; pa.fdd = wd;
    pa.x = x; pa.rw1 = rms_w1; pa.y1 = y1;
    prep_kernel<<<32768, 256, 0, stream>>>(pa);

    // --- dual GEMM (cat16, persistent): delta/b -> packed (A_t, b_t) ---
    gemm8p_kernel<0><<<256, 512, 0, stream>>>(
        y1, wcat_db, D_, D_, 8, delta_b, b_b, A_log, nullptr, ABp);

    // --- chunked fused liquid + PLIF scans ---
    scan_kernel<<<(B_ * SCAN_C * D_) / 256, 256, 0, stream>>>(ABp, log_tau, plif_thr, spikein);

    // --- dual GEMM (cat16, persistent): syn/gate -> x1 = x + syn*sigmoid(gate) ---
    gemm8p_kernel<1><<<256, 512, 0, stream>>>(
        spikein, wcat_sg, D_, D_, 8, syn_b, gate_b, x, nullptr, x1);

    // --- RMSNorm 2 (bf16 in) ---
    rmsnorm_bf_kernel<<<M_, 256, 0, stream>>>(x1, rms_w2, y2);

    // --- dual GEMM (cat16, persistent): ffn gate/up -> act = silu(g)*u ---
    gemm8p_kernel<2><<<256, 512, 0, stream>>>(
        y2, wcat_gu, D_, DFF_, 32, nullptr, nullptr, nullptr, nullptr, act);

    // --- GEMM (persistent, TPB=1): ffn down + residual -> out ---
    gemm8p_kernel<3><<<256, 512, 0, stream>>>(
        act, wd, DFF_, D_, 4, nullptr, nullptr, nullptr, x1, outF);
}